// Round 3
// baseline (402.870 us; speedup 1.0000x reference)
//
#include <hip/hip_runtime.h>

#define ED 64
#define HD 4
#define BD 1024
#define SNEG 22222
#define NT 1389              // ceil(SNEG/16)
#define SPAD (NT*16)         // 22224
#define SP1 (SNEG+1)         // 22223
#define LOGQ -3.81776242f    // log(-expm1(S*log1p(-1/V)))
#define NXB 16               // column-split groups
#define CPB 87               // ceil(NT/NXB)
#define NBLK 1024            // persistent grid: 4 blocks/CU on 256 CUs

typedef short bf16x8 __attribute__((ext_vector_type(8)));
typedef float f32x4 __attribute__((ext_vector_type(4)));

static __device__ __forceinline__ short f2bf(float f) {
    union { float f; unsigned u; } v; v.f = f;
    return (short)((v.u + 0x7FFFu + ((v.u >> 16) & 1u)) >> 16);
}

static __device__ __forceinline__ float fast_tanh(float x) {
    float ax = __builtin_fabsf(x);
    float e  = __expf(-2.f * ax);
    float t  = (1.f - e) / (1.f + e);
    return __builtin_copysignf(t, x);
}

// device-wide barrier: counter starts at 0 (memset), generation gen waits for gen*NBLK
static __device__ __forceinline__ void grid_bar(int* bar, int gen) {
    __syncthreads();
    if (threadIdx.x == 0) {
        __threadfence();                       // release: block's stores -> coherent point
        atomicAdd(bar, 1);                     // device-scope arrival
        while (__hip_atomic_load(bar, __ATOMIC_RELAXED, __HIP_MEMORY_SCOPE_AGENT) < gen*NBLK)
            __builtin_amdgcn_s_sleep(2);
        __threadfence();                       // acquire: invalidate stale cached lines
    }
    __syncthreads();
}

__global__ __launch_bounds__(256, 4) void k_fused(
        const float* __restrict__ inputs, const float* __restrict__ emb,
        const float* __restrict__ proj,   const float* __restrict__ mix,
        const float* __restrict__ biases, const int* __restrict__ label,
        const int* __restrict__ sids,
        short* __restrict__ W, short* __restrict__ A, float* __restrict__ bias_s,
        float* __restrict__ denom, int* __restrict__ bar,
        float* __restrict__ pi, float* __restrict__ tl,
        float* __restrict__ out) {
    __shared__ float s_in[64];
    __shared__ float s_proj[256];
    __shared__ float s_mix[4];
    __shared__ float s_red[256];
    __shared__ float s_cf[64];
    __shared__ float s_et[64];
    __shared__ float s_ls[256];

    const int blk = blockIdx.x, t = threadIdx.x;

    // ---------------- phase A: per-batch prep (batch b = blk) + gather slice
    {
        const int b = blk;
        if (t < 64) s_in[t] = inputs[b*64 + t];
        __syncthreads();
        const float* pr = proj + t*64;
        float dot = 0.f;
        #pragma unroll
        for (int k = 0; k < 64; k += 4)
            dot += s_in[k]*pr[k] + s_in[k+1]*pr[k+1] + s_in[k+2]*pr[k+2] + s_in[k+3]*pr[k+3];
        float val = fast_tanh(dot);
        s_proj[t] = val;
        A[(b*4 + (t >> 6))*64 + (t & 63)] = f2bf(val);
        if (t < 4) {
            const float* mr = mix + t*64;
            float md = 0.f;
            for (int k = 0; k < 64; ++k) md += s_in[k]*mr[k];
            s_mix[t] = md;
        }
        int lab = label[b];
        s_red[t] = s_proj[t] * emb[(size_t)lab*64 + (t & 63)];
        __syncthreads();
        if (t < 4) {
            float m = fmaxf(fmaxf(s_mix[0], s_mix[1]), fmaxf(s_mix[2], s_mix[3]));
            float e0 = __expf(s_mix[0]-m), e1 = __expf(s_mix[1]-m);
            float e2 = __expf(s_mix[2]-m), e3 = __expf(s_mix[3]-m);
            pi[b*4 + t] = __expf(s_mix[t]-m) / (e0+e1+e2+e3);
            float sum = 0.f;
            for (int k = 0; k < 64; ++k) sum += s_red[t*64 + k];
            tl[b*4 + t] = sum + biases[lab] - LOGQ;
        }
        // gather: one task per thread, 8 threads per sampled row
        int gt = blk*256 + t;
        if (gt < SPAD*8) {
            int s = gt >> 3, l8 = gt & 7;
            if (s < SNEG) {
                int id = sids[s];
                const float* src = emb + (size_t)id*64 + l8*8;
                bf16x8 o;
                #pragma unroll
                for (int j = 0; j < 8; ++j) o[j] = f2bf(src[j]);
                *(bf16x8*)(W + s*64 + l8*8) = o;
                if (l8 == 0) bias_s[s] = biases[id] - LOGQ;
            } else {
                bf16x8 o;
                #pragma unroll
                for (int j = 0; j < 8; ++j) o[j] = 0;
                *(bf16x8*)(W + s*64 + l8*8) = o;
                if (l8 == 0) bias_s[s] = -1e30f;
            }
        }
    }

    grid_bar(bar, 1);

    // ---------------- phase C: softmax denominators -----------------------
    const int bx = blk >> 6, by = blk & 63;      // bx: column group, by: row tile
    const int wave = t >> 6, lane = t & 63, g = lane >> 4, c = lane & 15;
    const int mbase = by*64 + wave*16;
    const bf16x8* a_ptr = (const bf16x8*)(A + (size_t)(mbase + c)*64);
    bf16x8 a0 = a_ptr[g];
    bf16x8 a1 = a_ptr[4 + g];
    const int st0 = bx*CPB;
    int st1 = st0 + CPB; if (st1 > NT) st1 = NT;
    {
        float s0 = 0.f, s1 = 0.f, s2 = 0.f, s3 = 0.f;
        for (int st = st0; st < st1; ++st) {
            const bf16x8* b_ptr = (const bf16x8*)(W + (size_t)(st*16 + c)*64);
            bf16x8 b0 = b_ptr[g], b1 = b_ptr[4 + g];
            f32x4 cc = {0.f, 0.f, 0.f, 0.f};
            cc = __builtin_amdgcn_mfma_f32_16x16x32_bf16(a0, b0, cc, 0, 0, 0);
            cc = __builtin_amdgcn_mfma_f32_16x16x32_bf16(a1, b1, cc, 0, 0, 0);
            float bias = bias_s[st*16 + c];
            s0 += __expf(cc[0] + bias);
            s1 += __expf(cc[1] + bias);
            s2 += __expf(cc[2] + bias);
            s3 += __expf(cc[3] + bias);
        }
        #pragma unroll
        for (int m = 1; m < 16; m <<= 1) {
            s0 += __shfl_xor(s0, m);
            s1 += __shfl_xor(s1, m);
            s2 += __shfl_xor(s2, m);
            s3 += __shfl_xor(s3, m);
        }
        if (c == 0) {
            atomicAdd(&denom[mbase + g*4 + 0], s0);
            atomicAdd(&denom[mbase + g*4 + 1], s1);
            atomicAdd(&denom[mbase + g*4 + 2], s2);
            atomicAdd(&denom[mbase + g*4 + 3], s3);
        }
    }

    grid_bar(bar, 2);

    // ---------------- phase E: coeff (block-local), out[:,0], loss, probs -
    if (t < 64) {
        int row = by*64 + t;
        float tt = tl[row];
        float et = __expf(tt);
        float d  = denom[row] + et;
        s_cf[t] = pi[row] / d;
        s_et[t] = et;
    }
    __syncthreads();
    if (bx == 0 && t < 16) {                     // out[:,0] for this block's 16 batches
        int b = by*16 + t;
        float p0 = 0.f;
        #pragma unroll
        for (int h = 0; h < 4; ++h) p0 += s_cf[t*4 + h] * s_et[t*4 + h];
        out[(size_t)b * SP1] = p0;
    }
    if (blk == 0) {                              // loss, redundant recompute, 1 block
        float lg = 0.f;
        for (int b = t; b < BD; b += 256) {
            float p0 = 0.f;
            #pragma unroll
            for (int h = 0; h < 4; ++h) {
                float tt = tl[b*4 + h];
                float et = __expf(tt);
                p0 += pi[b*4 + h] / (denom[b*4 + h] + et) * et;
            }
            lg += logf(p0);
        }
        s_ls[t] = lg;
        __syncthreads();
        for (int off = 128; off > 0; off >>= 1) {
            if (t < off) s_ls[t] += s_ls[t + off];
            __syncthreads();
        }
        if (t == 0) out[(size_t)BD * SP1] = -s_ls[0] * (1.f / (float)BD);
    }
    {
        float cf0 = s_cf[wave*16 + g*4 + 0];
        float cf1 = s_cf[wave*16 + g*4 + 1];
        float cf2 = s_cf[wave*16 + g*4 + 2];
        float cf3 = s_cf[wave*16 + g*4 + 3];
        int b = (mbase >> 2) + g;
        float* orow = out + (size_t)b * SP1 + 1;
        for (int st = st0; st < st1; ++st) {
            const bf16x8* b_ptr = (const bf16x8*)(W + (size_t)(st*16 + c)*64);
            bf16x8 b0 = b_ptr[g], b1 = b_ptr[4 + g];
            f32x4 cc = {0.f, 0.f, 0.f, 0.f};
            cc = __builtin_amdgcn_mfma_f32_16x16x32_bf16(a0, b0, cc, 0, 0, 0);
            cc = __builtin_amdgcn_mfma_f32_16x16x32_bf16(a1, b1, cc, 0, 0, 0);
            int scol = st*16 + c;
            float bias = bias_s[scol];
            float p = cf0*__expf(cc[0] + bias) + cf1*__expf(cc[1] + bias)
                    + cf2*__expf(cc[2] + bias) + cf3*__expf(cc[3] + bias);
            if (scol < SNEG) orow[scol] = p;
        }
    }
}

extern "C" void kernel_launch(void* const* d_in, const int* in_sizes, int n_in,
                              void* d_out, int out_size, void* d_ws, size_t ws_size,
                              hipStream_t stream) {
    const float* inputs = (const float*)d_in[0];
    const float* emb    = (const float*)d_in[1];
    const float* proj   = (const float*)d_in[2];
    const float* mix    = (const float*)d_in[3];
    const float* biases = (const float*)d_in[4];
    const int*   label  = (const int*)d_in[5];
    const int*   sids   = (const int*)d_in[6];
    float* out = (float*)d_out;

    char* ws = (char*)d_ws;
    short* W      = (short*)(ws);                      // 2,844,672 B
    short* A      = (short*)(ws + 2844672);            // 524,288 B
    float* bias_s = (float*)(ws + 3368960);            // 88,896 B
    float* denom  = (float*)(ws + 3457856);            // 16,384 B
    int*   bar    = (int*)  (ws + 3474240);            // 4 B (+pad)
    float* pi     = (float*)(ws + 3474304);            // 16,384 B
    float* tl     = (float*)(ws + 3490688);            // 16,384 B

    // zero denom + barrier counter (16,384 + pad = 16,448 B starting at denom)
    hipMemsetAsync(denom, 0, 16448, stream);
    k_fused<<<NBLK, 256, 0, stream>>>(inputs, emb, proj, mix, biases, label, sids,
                                      W, A, bias_s, denom, bar, pi, tl, out);
}

// Round 4
// 158.745 us; speedup vs baseline: 2.5378x; 2.5378x over previous
//
#include <hip/hip_runtime.h>

#define ED 64
#define HD 4
#define BD 1024
#define SNEG 22222
#define NT 1389              // ceil(SNEG/16)
#define SPAD (NT*16)         // 22224
#define SP1 (SNEG+1)         // 22223
#define LOGQ -3.81776242f    // log(-expm1(S*log1p(-1/V)))
#define NXB 32               // column groups
#define CPB 44               // ceil(NT/NXB)

typedef short bf16x8 __attribute__((ext_vector_type(8)));
typedef float f32x4 __attribute__((ext_vector_type(4)));

static __device__ __forceinline__ short f2bf(float f) {
    union { float f; unsigned u; } v; v.f = f;
    return (short)((v.u + 0x7FFFu + ((v.u >> 16) & 1u)) >> 16);
}

static __device__ __forceinline__ float fast_tanh(float x) {
    float ax = __builtin_fabsf(x);
    float e  = __expf(-2.f * ax);
    float t  = (1.f - e) / (1.f + e);
    return __builtin_copysignf(t, x);
}

// ---------------- kernel 1: fused setup (prep + gather + zero denom) ------
__global__ __launch_bounds__(256) void k_setup(
        const float* __restrict__ inputs, const float* __restrict__ emb,
        const float* __restrict__ proj,   const float* __restrict__ mix,
        const float* __restrict__ biases, const int* __restrict__ label,
        const int* __restrict__ sids,
        short* __restrict__ A, float* __restrict__ pi, float* __restrict__ tl,
        short* __restrict__ W, float* __restrict__ bias_s,
        float* __restrict__ denom) {
    if (blockIdx.x < BD) {
        int b = blockIdx.x, t = threadIdx.x;
        __shared__ float s_in[64];
        __shared__ float s_proj[256];
        __shared__ float s_mix[4];
        __shared__ float s_red[256];
        if (t < 64) s_in[t] = inputs[b*64 + t];
        __syncthreads();
        const float* pr = proj + t*64;
        float dot = 0.f;
        #pragma unroll
        for (int k = 0; k < 64; k += 4)
            dot += s_in[k]*pr[k] + s_in[k+1]*pr[k+1] + s_in[k+2]*pr[k+2] + s_in[k+3]*pr[k+3];
        float val = fast_tanh(dot);
        s_proj[t] = val;
        A[(b*4 + (t >> 6))*64 + (t & 63)] = f2bf(val);
        if (t < 4) {
            const float* mr = mix + t*64;
            float md = 0.f;
            for (int k = 0; k < 64; ++k) md += s_in[k]*mr[k];
            s_mix[t] = md;
        }
        int lab = label[b];
        s_red[t] = s_proj[t] * emb[(size_t)lab*64 + (t & 63)];
        __syncthreads();
        if (t < 4) {
            float m = fmaxf(fmaxf(s_mix[0], s_mix[1]), fmaxf(s_mix[2], s_mix[3]));
            float e0 = __expf(s_mix[0]-m), e1 = __expf(s_mix[1]-m);
            float e2 = __expf(s_mix[2]-m), e3 = __expf(s_mix[3]-m);
            pi[b*4 + t] = __expf(s_mix[t]-m) / (e0+e1+e2+e3);
            float sum = 0.f;
            for (int k = 0; k < 64; ++k) sum += s_red[t*64 + k];
            tl[b*4 + t] = sum + biases[lab] - LOGQ;
        }
    } else {
        int t = (blockIdx.x - BD)*256 + threadIdx.x;
        if (t < BD*HD) denom[t] = 0.f;
        int s = t >> 3, l8 = t & 7;
        if (s >= SPAD) return;
        if (s < SNEG) {
            int id = sids[s];
            const float* src = emb + (size_t)id*64 + l8*8;
            bf16x8 o;
            #pragma unroll
            for (int j = 0; j < 8; ++j) o[j] = f2bf(src[j]);
            *(bf16x8*)(W + s*64 + l8*8) = o;
            if (l8 == 0) bias_s[s] = biases[id] - LOGQ;
        } else {
            bf16x8 o;
            #pragma unroll
            for (int j = 0; j < 8; ++j) o[j] = 0;
            *(bf16x8*)(W + s*64 + l8*8) = o;
            if (l8 == 0) bias_s[s] = -1e30f;
        }
    }
}

// ---------------- kernel 2: denominators -----------------------------------
// block: 64 rows (4 MFMA row-tiles, all owned by EVERY wave) x CPB*16 cols.
// wave w covers tiles st0+w, st0+w+4, ... : per iter 2 loads -> 8 MFMA -> 16 exp.
__global__ __launch_bounds__(256) void k_denom(
        const short* __restrict__ A, const short* __restrict__ W,
        const float* __restrict__ bias_s, float* __restrict__ denom) {
    const int wave = threadIdx.x >> 6, lane = threadIdx.x & 63;
    const int g = lane >> 4, c = lane & 15;
    const int rbase = blockIdx.y * 64;
    bf16x8 a0[4], a1[4];
    #pragma unroll
    for (int t4 = 0; t4 < 4; ++t4) {
        const bf16x8* ap = (const bf16x8*)(A + (size_t)(rbase + t4*16 + c)*64);
        a0[t4] = ap[g]; a1[t4] = ap[4 + g];
    }
    float s[16];
    #pragma unroll
    for (int i = 0; i < 16; ++i) s[i] = 0.f;

    int st  = blockIdx.x*CPB + wave;
    int st1 = blockIdx.x*CPB + CPB; if (st1 > NT) st1 = NT;
    if (st < st1) {
        const bf16x8* bp = (const bf16x8*)(W + (size_t)(st*16 + c)*64);
        bf16x8 b0 = bp[g], b1 = bp[4 + g];
        float bias = bias_s[st*16 + c];
        while (st < st1) {
            int nst = st + 4;
            int pst = nst < st1 ? nst : st;          // clamped prefetch addr
            const bf16x8* np = (const bf16x8*)(W + (size_t)(pst*16 + c)*64);
            bf16x8 n0 = np[g], n1 = np[4 + g];
            float nbias = bias_s[pst*16 + c];
            #pragma unroll
            for (int t4 = 0; t4 < 4; ++t4) {
                f32x4 z = {0.f, 0.f, 0.f, 0.f};
                z = __builtin_amdgcn_mfma_f32_16x16x32_bf16(a0[t4], b0, z, 0, 0, 0);
                z = __builtin_amdgcn_mfma_f32_16x16x32_bf16(a1[t4], b1, z, 0, 0, 0);
                s[t4*4+0] += __expf(z[0] + bias);
                s[t4*4+1] += __expf(z[1] + bias);
                s[t4*4+2] += __expf(z[2] + bias);
                s[t4*4+3] += __expf(z[3] + bias);
            }
            b0 = n0; b1 = n1; bias = nbias; st = nst;
        }
    }
    #pragma unroll
    for (int m = 1; m < 16; m <<= 1)
        #pragma unroll
        for (int i = 0; i < 16; ++i) s[i] += __shfl_xor(s[i], m);
    if (c == 0) {
        #pragma unroll
        for (int t4 = 0; t4 < 4; ++t4)
            #pragma unroll
            for (int r = 0; r < 4; ++r)
                atomicAdd(&denom[rbase + t4*16 + g*4 + r], s[t4*4+r]);
    }
}

// ---------------- kernel 3: probs + out[:,0] + loss -------------------------
__global__ __launch_bounds__(256) void k_probs(
        const short* __restrict__ A, const short* __restrict__ W,
        const float* __restrict__ bias_s, const float* __restrict__ pi,
        const float* __restrict__ tl, const float* __restrict__ denom,
        float* __restrict__ out) {
    const int t = threadIdx.x;
    const int wave = t >> 6, lane = t & 63;
    const int g = lane >> 4, c = lane & 15;
    const int rbase = blockIdx.y * 64;
    __shared__ float s_cf[64];
    __shared__ float s_et[64];
    __shared__ float s_ls[4];

    if (t < 64) {
        int row = rbase + t;
        float et = __expf(tl[row]);
        float d  = denom[row] + et;
        s_cf[t] = pi[row] / d;
        s_et[t] = et;
    }
    __syncthreads();
    if (blockIdx.x == 0 && t < 16) {             // out[:,0] for this row-block
        float p0 = 0.f;
        #pragma unroll
        for (int h = 0; h < 4; ++h) p0 += s_cf[t*4 + h] * s_et[t*4 + h];
        out[(size_t)(rbase/4 + t) * SP1] = p0;
    }
    if (blockIdx.x == 0 && blockIdx.y == 0) {    // loss (redundant recompute)
        float lg = 0.f;
        for (int b = t; b < BD; b += 256) {
            float p0 = 0.f;
            #pragma unroll
            for (int h = 0; h < 4; ++h) {
                float et = __expf(tl[b*4 + h]);
                p0 += pi[b*4 + h] / (denom[b*4 + h] + et) * et;
            }
            lg += logf(p0);
        }
        #pragma unroll
        for (int m = 1; m < 64; m <<= 1) lg += __shfl_xor(lg, m);
        if (lane == 0) s_ls[wave] = lg;
        __syncthreads();
        if (t == 0)
            out[(size_t)BD * SP1] = -(s_ls[0]+s_ls[1]+s_ls[2]+s_ls[3]) * (1.f/(float)BD);
    }

    bf16x8 a0[4], a1[4];
    float cf[4][4];
    float* orow[4];
    #pragma unroll
    for (int t4 = 0; t4 < 4; ++t4) {
        const bf16x8* ap = (const bf16x8*)(A + (size_t)(rbase + t4*16 + c)*64);
        a0[t4] = ap[g]; a1[t4] = ap[4 + g];
        #pragma unroll
        for (int r = 0; r < 4; ++r) cf[t4][r] = s_cf[t4*16 + g*4 + r];
        orow[t4] = out + (size_t)(rbase/4 + t4*4 + g) * SP1 + 1;
    }

    int st  = blockIdx.x*CPB + wave;
    int st1 = blockIdx.x*CPB + CPB; if (st1 > NT) st1 = NT;
    if (st < st1) {
        const bf16x8* bp = (const bf16x8*)(W + (size_t)(st*16 + c)*64);
        bf16x8 b0 = bp[g], b1 = bp[4 + g];
        float bias = bias_s[st*16 + c];
        while (st < st1) {
            int nst = st + 4;
            int pst = nst < st1 ? nst : st;
            const bf16x8* np = (const bf16x8*)(W + (size_t)(pst*16 + c)*64);
            bf16x8 n0 = np[g], n1 = np[4 + g];
            float nbias = bias_s[pst*16 + c];
            int scol = st*16 + c;
            bool ok = scol < SNEG;
            #pragma unroll
            for (int t4 = 0; t4 < 4; ++t4) {
                f32x4 z = {0.f, 0.f, 0.f, 0.f};
                z = __builtin_amdgcn_mfma_f32_16x16x32_bf16(a0[t4], b0, z, 0, 0, 0);
                z = __builtin_amdgcn_mfma_f32_16x16x32_bf16(a1[t4], b1, z, 0, 0, 0);
                float p = cf[t4][0]*__expf(z[0] + bias) + cf[t4][1]*__expf(z[1] + bias)
                        + cf[t4][2]*__expf(z[2] + bias) + cf[t4][3]*__expf(z[3] + bias);
                if (ok) __builtin_nontemporal_store(p, &orow[t4][scol]);
            }
            b0 = n0; b1 = n1; bias = nbias; st = nst;
        }
    }
}

extern "C" void kernel_launch(void* const* d_in, const int* in_sizes, int n_in,
                              void* d_out, int out_size, void* d_ws, size_t ws_size,
                              hipStream_t stream) {
    const float* inputs = (const float*)d_in[0];
    const float* emb    = (const float*)d_in[1];
    const float* proj   = (const float*)d_in[2];
    const float* mix    = (const float*)d_in[3];
    const float* biases = (const float*)d_in[4];
    const int*   label  = (const int*)d_in[5];
    const int*   sids   = (const int*)d_in[6];
    float* out = (float*)d_out;

    char* ws = (char*)d_ws;
    short* W      = (short*)(ws);                      // 2,844,672 B
    short* A      = (short*)(ws + 2844672);            // 524,288 B
    float* bias_s = (float*)(ws + 3368960);            // 88,896 B
    float* denom  = (float*)(ws + 3457856);            // 16,384 B
    float* pi     = (float*)(ws + 3474304);            // 16,384 B
    float* tl     = (float*)(ws + 3490688);            // 16,384 B

    int gather_blocks = (SPAD*8 + 255)/256;            // 695
    k_setup<<<BD + gather_blocks, 256, 0, stream>>>(
        inputs, emb, proj, mix, biases, label, sids, A, pi, tl, W, bias_s, denom);
    k_denom<<<dim3(NXB, 64), 256, 0, stream>>>(A, W, bias_s, denom);
    k_probs<<<dim3(NXB, 64), 256, 0, stream>>>(A, W, bias_s, pi, tl, denom, out);
}